// Round 1
// baseline (1916.406 us; speedup 1.0000x reference)
//
#include <hip/hip_runtime.h>
#include <math.h>

#define NT 365
#define NGRID 30000
#define NX 16
#define HID 256

// Pre-kernel: collapse Wo@Wh -> w_eff (256), Wo@bh + bo -> b_eff (scalar).
// ws layout: ws[0..255] = w_eff, ws[256] = b_eff.
__global__ void weff_kernel(const float* __restrict__ Wh, const float* __restrict__ Wo,
                            const float* __restrict__ bh, const float* __restrict__ bo,
                            float* __restrict__ ws) {
    int h = threadIdx.x;  // 256 threads
    float acc = 0.f;
    for (int j = 0; j < HID; ++j)
        acc = fmaf(Wo[j], Wh[j * HID + h], acc);
    ws[h] = acc;

    __shared__ float prod[HID];
    prod[h] = Wo[h] * bh[h];
    __syncthreads();
    if (h == 0) {
        float b = bo[0];
        for (int j = 0; j < HID; ++j) b += prod[j];
        ws[HID] = b;
    }
}

// Main kernel: one wave per grid cell, full time loop per wave.
// Lane l, reg r holds hidden unit h = r*64 + l. Weights resident in VGPRs.
__global__ __launch_bounds__(256, 4) void rnn_closed_loop(
    const float* __restrict__ x,   // (NT, NGRID, NX)
    const float* __restrict__ y,   // (NT, NGRID, 1) with NaN = missing
    const float* __restrict__ Wi,  // (HID, NX+1) row-major
    const float* __restrict__ bi,  // (HID)
    const float* __restrict__ ws,  // w_eff[256], b_eff
    float* __restrict__ out)       // (NT, NGRID, 1)
{
    const int lane = threadIdx.x & 63;
    const int wv   = threadIdx.x >> 6;
    int cell = blockIdx.x * 4 + wv;            // 7500 blocks * 4 waves = 30000
    cell = __builtin_amdgcn_readfirstlane(cell);

    // Load per-lane weights once (h = r*64 + lane).
    float wi[4][16], wiy[4], bir[4], wef[4];
#pragma unroll
    for (int r = 0; r < 4; ++r) {
        const int h = r * 64 + lane;
        const float* wrow = Wi + h * (NX + 1);
#pragma unroll
        for (int k = 0; k < 16; ++k) wi[r][k] = wrow[k];
        wiy[r] = wrow[16];
        bir[r] = bi[h];
        wef[r] = ws[h];
    }
    const float b_eff = ws[HID];

    float yt = 0.f;                            // carried scalar prediction
    const float* xp = x + (size_t)cell * NX;
    const float* yp = y + cell;
    float*       op = out + cell;

    for (int t = 0; t < NT; ++t) {
        // Wave-uniform loads of this cell's inputs (scalar pipe).
        float xk[16];
#pragma unroll
        for (int k = 0; k < 16; ++k) xk[k] = xp[k];
        const float yo = *yp;
        const float y_in = (yo == yo) ? yo : yt;   // fillObs: NaN -> keep yt

        float p = 0.f;
#pragma unroll
        for (int r = 0; r < 4; ++r) {
            float acc = fmaf(wiy[r], y_in, bir[r]);
#pragma unroll
            for (int k = 0; k < 16; ++k)
                acc = fmaf(wi[r][k], xk[k], acc);
            acc = fmaxf(acc, 0.f);                 // relu
            p = fmaf(wef[r], acc, p);              // w_eff · ht (partial)
        }
        // Butterfly reduce across the 64 lanes -> ynew broadcast to all lanes.
#pragma unroll
        for (int off = 32; off >= 1; off >>= 1)
            p += __shfl_xor(p, off, 64);

        const float ynew = p + b_eff;
        yt = ynew;
        if (lane == 0) *op = ynew;

        xp += (size_t)NGRID * NX;
        yp += NGRID;
        op += NGRID;
    }
}

extern "C" void kernel_launch(void* const* d_in, const int* in_sizes, int n_in,
                              void* d_out, int out_size, void* d_ws, size_t ws_size,
                              hipStream_t stream) {
    const float* x  = (const float*)d_in[0];
    const float* y  = (const float*)d_in[1];
    const float* Wi = (const float*)d_in[2];
    const float* bi = (const float*)d_in[3];
    const float* Wh = (const float*)d_in[4];
    const float* bh = (const float*)d_in[5];
    const float* Wo = (const float*)d_in[6];
    const float* bo = (const float*)d_in[7];
    float* out = (float*)d_out;
    float* ws  = (float*)d_ws;

    weff_kernel<<<1, HID, 0, stream>>>(Wh, Wo, bh, bo, ws);
    rnn_closed_loop<<<NGRID / 4, 256, 0, stream>>>(x, y, Wi, bi, ws, out);
}

// Round 2
// 538.161 us; speedup vs baseline: 3.5610x; 3.5610x over previous
//
#include <hip/hip_runtime.h>
#include <math.h>

#define NT 365
#define NGRID 30000
#define NX 16
#define HID 256
#define CB 16   // cells per wave

typedef __attribute__((ext_vector_type(8))) short bf16x8;
typedef __attribute__((ext_vector_type(4))) float f32x4;

static __device__ __forceinline__ short f2bf(float f) {
    union { float f; unsigned u; } v; v.f = f;
    unsigned r = (v.u + 0x7fffu + ((v.u >> 16) & 1u)) >> 16;  // RNE
    return (short)r;
}

// Pre-kernel: w_eff = Wo@Wh (256), b_eff = Wo@bh + bo (scalar).
// ws layout: ws[0..255] = w_eff, ws[256] = b_eff.
__global__ void weff_kernel(const float* __restrict__ Wh, const float* __restrict__ Wo,
                            const float* __restrict__ bh, const float* __restrict__ bo,
                            float* __restrict__ ws) {
    int h = threadIdx.x;  // 256 threads
    float acc = 0.f;
    for (int j = 0; j < HID; ++j)
        acc = fmaf(Wo[j], Wh[j * HID + h], acc);
    ws[h] = acc;

    __shared__ float prod[HID];
    prod[h] = Wo[h] * bh[h];
    __syncthreads();
    if (h == 0) {
        float b = bo[0];
        for (int j = 0; j < HID; ++j) b += prod[j];
        ws[HID] = b;
    }
}

// One wave = 16 cells, full 365-step loop. MFMA does the (256 x 17) input GEMM.
// B logical layout: K x 16cells, K: 0..15 = x feats, 16 = y_in, 17 = 1.0 (bias), rest 0.
// A = Wi rows (bf16), bias folded at k=17. Both operands packed with the same
// (hi=lane>>4, j) -> k = hi*8+j map, so any HW k-permutation cancels.
__global__ __launch_bounds__(64, 2) void rnn_mfma(
    const float* __restrict__ x,   // (NT, NGRID, NX)
    const float* __restrict__ y,   // (NT, NGRID, 1), NaN = missing
    const float* __restrict__ Wi,  // (HID, NX+1)
    const float* __restrict__ bi,  // (HID)
    const float* __restrict__ ws,  // w_eff[256], b_eff
    float* __restrict__ out)       // (NT, NGRID, 1)
{
    const int lane = threadIdx.x & 63;
    const int c    = lane & 15;    // cell within batch / A-row within tile
    const int hi   = lane >> 4;
    const int cell0 = blockIdx.x * CB;

    // ---- A fragments (Wi + bias column), resident: 16 tiles x 4 VGPRs ----
    bf16x8 a[16];
#pragma unroll
    for (int m = 0; m < 16; ++m) {
        const int row = m * 16 + c;            // A row = lane&15
        const float* wrow = Wi + row * (NX + 1);
        bf16x8 av;
        if (hi < 2) {
#pragma unroll
            for (int j = 0; j < 8; ++j) av[j] = f2bf(wrow[hi * 8 + j]);
        } else if (hi == 2) {
            av[0] = f2bf(wrow[16]);            // k=16: weight on y_in
            av[1] = f2bf(bi[row]);             // k=17: bias (x constant 1.0)
#pragma unroll
            for (int j = 2; j < 8; ++j) av[j] = 0;
        } else {
#pragma unroll
            for (int j = 0; j < 8; ++j) av[j] = 0;
        }
        a[m] = av;
    }

    // w_eff for this lane's C-layout rows: hidden = 16m + hi*4 + r
    float wef[16][4];
#pragma unroll
    for (int m = 0; m < 16; ++m)
#pragma unroll
        for (int r = 0; r < 4; ++r)
            wef[m][r] = ws[m * 16 + hi * 4 + r];
    const float b_eff = ws[HID];

    // per-lane x source: lanes hi<2 load 8 floats (feats hi*8..hi*8+7) of cell c
    const size_t xoff = (size_t)(cell0 + c) * NX + hi * 8;
    const float* yb = y + cell0 + c;
    float*       ob = out + cell0 + c;

    float4 xa = {0,0,0,0}, xb = {0,0,0,0};
    if (hi < 2) {
        const float4* p = (const float4*)(x + xoff);
        xa = p[0]; xb = p[1];
    }
    float yo = yb[0];
    float yprev = 0.f;

    for (int t = 0; t < NT; ++t) {
        // prefetch t+1 into regs (hide HBM latency under this step's compute)
        float4 nxa = xa, nxb = xb; float nyo = yo;
        if (t + 1 < NT) {
            if (hi < 2) {
                const float4* p = (const float4*)(x + (size_t)(t + 1) * NGRID * NX + xoff);
                nxa = p[0]; nxb = p[1];
            }
            nyo = yb[(size_t)(t + 1) * NGRID];
        }

        const float y_in = (yo == yo) ? yo : yprev;   // fillObs

        // ---- B fragment ----
        bf16x8 b;
        if (hi < 2) {
            b[0] = f2bf(xa.x); b[1] = f2bf(xa.y); b[2] = f2bf(xa.z); b[3] = f2bf(xa.w);
            b[4] = f2bf(xb.x); b[5] = f2bf(xb.y); b[6] = f2bf(xb.z); b[7] = f2bf(xb.w);
        } else if (hi == 2) {
            b[0] = f2bf(y_in);
            b[1] = (short)0x3F80;   // 1.0 -> bias column
#pragma unroll
            for (int j = 2; j < 8; ++j) b[j] = 0;
        } else {
#pragma unroll
            for (int j = 0; j < 8; ++j) b[j] = 0;
        }

        // ---- hidden layer: 16 independent MFMAs ----
        const f32x4 zero = {0.f, 0.f, 0.f, 0.f};
        f32x4 acc[16];
#pragma unroll
        for (int m = 0; m < 16; ++m)
            acc[m] = __builtin_amdgcn_mfma_f32_16x16x32_bf16(a[m], b, zero, 0, 0, 0);

        // ---- relu + w_eff dot (4 independent chains for ILP) ----
        float p0 = 0.f, p1 = 0.f, p2 = 0.f, p3 = 0.f;
#pragma unroll
        for (int m = 0; m < 16; ++m) {
            p0 = fmaf(wef[m][0], fmaxf(acc[m][0], 0.f), p0);
            p1 = fmaf(wef[m][1], fmaxf(acc[m][1], 0.f), p1);
            p2 = fmaf(wef[m][2], fmaxf(acc[m][2], 0.f), p2);
            p3 = fmaf(wef[m][3], fmaxf(acc[m][3], 0.f), p3);
        }
        float p = (p0 + p1) + (p2 + p3);

        // sum the 4 hi-groups per cell; result broadcast to all lanes
        p += __shfl_xor(p, 16, 64);
        p += __shfl_xor(p, 32, 64);
        const float ynew = p + b_eff;

        if (lane < 16) ob[(size_t)t * NGRID] = ynew;

        yprev = ynew;
        xa = nxa; xb = nxb; yo = nyo;
    }
}

extern "C" void kernel_launch(void* const* d_in, const int* in_sizes, int n_in,
                              void* d_out, int out_size, void* d_ws, size_t ws_size,
                              hipStream_t stream) {
    const float* x  = (const float*)d_in[0];
    const float* y  = (const float*)d_in[1];
    const float* Wi = (const float*)d_in[2];
    const float* bi = (const float*)d_in[3];
    const float* Wh = (const float*)d_in[4];
    const float* bh = (const float*)d_in[5];
    const float* Wo = (const float*)d_in[6];
    const float* bo = (const float*)d_in[7];
    float* out = (float*)d_out;
    float* ws  = (float*)d_ws;

    weff_kernel<<<1, HID, 0, stream>>>(Wh, Wo, bh, bo, ws);
    rnn_mfma<<<NGRID / CB, 64, 0, stream>>>(x, y, Wi, bi, ws, out);
}